// Round 1
// baseline (999.447 us; speedup 1.0000x reference)
//
#include <hip/hip_runtime.h>

typedef unsigned short u16;

constexpr int kN = 32, kC = 256, kT = 256, kV = 25, kCI = 128;
constexpr int kTV = kT * kV;        // 6400
constexpr int kCIV = kCI * kV;      // 3200
constexpr int kSAMP = kN * kT * kV; // 204800
constexpr int SYY_BLOCKS = 400;

__device__ __forceinline__ float bf2f(u16 v) {
  return __uint_as_float(((unsigned)v) << 16);
}
__device__ __forceinline__ u16 f2bf(float f) {
  unsigned u = __float_as_uint(f);
  return (u16)((u + 0x7FFFu + ((u >> 16) & 1u)) >> 16);
}

// ---------- 1) xmean[n,c,t] = mean_v x[n,c,t,v] ----------
__global__ __launch_bounds__(256) void k_xmean(const float* __restrict__ x, float* __restrict__ xmean) {
  int i = blockIdx.x * 256 + threadIdx.x;  // over N*C*T
  const float* p = x + (size_t)i * kV;
  float s = 0.f;
#pragma unroll
  for (int v = 0; v < kV; ++v) s += p[v];
  xmean[i] = s * (1.0f / kV);
}

// ---------- 2) theta[n,o,t], phi[n,o,t] ----------
__global__ __launch_bounds__(256) void k_thetaphi(
    const float* __restrict__ xmean, const float* __restrict__ Wth, const float* __restrict__ bth,
    const float* __restrict__ Wph, const float* __restrict__ bph,
    float* __restrict__ theta, float* __restrict__ phi) {
  int n = blockIdx.x >> 7;
  int o = blockIdx.x & 127;
  int t = threadIdx.x;
  __shared__ float wt[kC], wp[kC];
  wt[t] = Wth[o * kC + t];
  wp[t] = Wph[o * kC + t];
  __syncthreads();
  const float* xm = xmean + (size_t)n * kC * kT + t;
  float at = 0.f, ap = 0.f;
#pragma unroll 8
  for (int c = 0; c < kC; ++c) {
    float xv = xm[c * kT];  // coalesced across t
    at = fmaf(wt[c], xv, at);
    ap = fmaf(wp[c], xv, ap);
  }
  size_t idx = ((size_t)n * kCI + o) * kT + t;
  theta[idx] = at + bth[o];
  phi[idx] = ap + bph[o];
}

// ---------- 3) f[n,t,:] = softmax(theta[n,:,t] . phi[n,:,:]) ----------
__global__ __launch_bounds__(256) void k_fsm(const float* __restrict__ theta, const float* __restrict__ phi,
                                             float* __restrict__ f) {
  int n = blockIdx.x >> 8;
  int t = blockIdx.x & 255;
  int tp = threadIdx.x;
  __shared__ float th[kCI];
  __shared__ float red[256];
  if (tp < kCI) th[tp] = theta[((size_t)n * kCI + tp) * kT + t];
  __syncthreads();
  const float* ph = phi + (size_t)n * kCI * kT + tp;
  float acc = 0.f;
#pragma unroll 8
  for (int o = 0; o < kCI; ++o) acc = fmaf(th[o], ph[o * kT], acc);
  red[tp] = acc;
  __syncthreads();
  for (int s = 128; s > 0; s >>= 1) {
    if (tp < s) red[tp] = fmaxf(red[tp], red[tp + s]);
    __syncthreads();
  }
  float m = red[0];
  __syncthreads();
  float e = __expf(acc - m);
  red[tp] = e;
  __syncthreads();
  for (int s = 128; s > 0; s >>= 1) {
    if (tp < s) red[tp] += red[tp + s];
    __syncthreads();
  }
  f[(size_t)blockIdx.x * 256 + tp] = e * (1.0f / red[0]);
}

// ---------- tiled fp32 GEMM: C_n = A @ B_n, A row-major [M,K], B row-major [K,NNd] ----------
// MODE 0: g conv  (A=Wg shared, B=x f32, +bias, store bf16 scatter to [N,T,CI,V])
// MODE 1: y=attn  (A=f per-n,  B=g2 bf16, store bf16 scatter to [N,CI,T,V])
// MODE 2: wy conv (A=Ww shared,B=y bf16,  fused BN + residual, store f32 [N,C,T,V])
template <int BM, int M_, int K_, int NNd, int MODE, typename TB>
__global__ __launch_bounds__(256) void k_gemm(
    const float* __restrict__ A_all, const TB* __restrict__ B_all, const float* __restrict__ bias,
    void* __restrict__ outp, const float* __restrict__ scale, const float* __restrict__ shift,
    const float* __restrict__ xres) {
  constexpr int MR = BM / 16;
  const int n = blockIdx.z;
  const int m0 = blockIdx.y * BM;
  const int n0 = blockIdx.x * 64;
  __shared__ float As[16][BM + 4];
  __shared__ float Bs[16][64];
  const float* A = (MODE == 1) ? A_all + (size_t)n * M_ * K_ : A_all;
  const TB* B = B_all + (size_t)n * K_ * NNd;
  const int tid = threadIdx.x;
  const int tx = tid & 15, ty = tid >> 4;
  float acc[MR][4];
#pragma unroll
  for (int i = 0; i < MR; ++i)
#pragma unroll
    for (int j = 0; j < 4; ++j) acc[i][j] = 0.f;

  for (int k0 = 0; k0 < K_; k0 += 16) {
#pragma unroll
    for (int i = 0; i < BM / 16; ++i) {
      int e = tid + i * 256;
      int r = e >> 4, c = e & 15;
      As[c][r] = A[(size_t)(m0 + r) * K_ + (k0 + c)];
    }
#pragma unroll
    for (int i = 0; i < 4; ++i) {
      int e = tid + i * 256;
      int r = e >> 6, c = e & 63;
      float v;
      if constexpr (sizeof(TB) == 2)
        v = bf2f(B[(size_t)(k0 + r) * NNd + (n0 + c)]);
      else
        v = B[(size_t)(k0 + r) * NNd + (n0 + c)];
      Bs[r][c] = v;
    }
    __syncthreads();
#pragma unroll
    for (int k = 0; k < 16; ++k) {
      float a[MR], b[4];
#pragma unroll
      for (int ch = 0; ch < MR / 8; ++ch) {
        *(float4*)&a[ch * 8] = *(const float4*)&As[k][ch * 128 + ty * 8];
        *(float4*)&a[ch * 8 + 4] = *(const float4*)&As[k][ch * 128 + ty * 8 + 4];
      }
      *(float4*)&b[0] = *(const float4*)&Bs[k][tx * 4];
#pragma unroll
      for (int i = 0; i < MR; ++i)
#pragma unroll
        for (int j = 0; j < 4; ++j) acc[i][j] = fmaf(a[i], b[j], acc[i][j]);
    }
    __syncthreads();
  }
#pragma unroll
  for (int i = 0; i < MR; ++i) {
    int row = m0 + (i >> 3) * 128 + ty * 8 + (i & 7);
#pragma unroll
    for (int j = 0; j < 4; ++j) {
      int col = n0 + tx * 4 + j;
      float v = acc[i][j];
      if constexpr (MODE == 0) {
        v += bias[row];
        int t = col / kV, vv = col - t * kV;
        ((u16*)outp)[(((size_t)n * kT + t) * kCI + row) * kV + vv] = f2bf(v);
      } else if constexpr (MODE == 1) {
        int ci = col / kV, vv = col - ci * kV;
        ((u16*)outp)[(((size_t)n * kCI + ci) * kT + row) * kV + vv] = f2bf(v);
      } else {
        size_t idx = (size_t)n * kC * kTV + (size_t)row * kTV + col;
        ((float*)outp)[idx] = v * scale[row] + shift[row] + xres[idx];
      }
    }
  }
}

// ---------- Syy = Y Y^T (128x128) and Sy partials over 204800 samples ----------
__global__ __launch_bounds__(256) void k_syy(const u16* __restrict__ y, float* __restrict__ part_syy,
                                             float* __restrict__ part_sy) {
  __shared__ float Ys[64][132];
  const int tid = threadIdx.x;
  const int tx = tid & 15, ty = tid >> 4;
  float acc[8][8];
#pragma unroll
  for (int i = 0; i < 8; ++i)
#pragma unroll
    for (int j = 0; j < 8; ++j) acc[i][j] = 0.f;
  float syacc = 0.f;
  for (int ch = 0; ch < 8; ++ch) {
    int chunk = blockIdx.x * 8 + ch;  // 3200 chunks of 64 samples
    int n = chunk / 100;
    int r0 = (chunk % 100) * 64;
    const u16* ybase = y + (size_t)n * kCI * kTV + r0;
#pragma unroll
    for (int i = 0; i < 32; ++i) {
      int e = tid + i * 256;
      int ci = e >> 6, k = e & 63;
      Ys[k][ci] = bf2f(ybase[(size_t)ci * kTV + k]);
    }
    __syncthreads();
#pragma unroll 8
    for (int k = 0; k < 64; ++k) {
      float a[8], b[8];
      *(float4*)&a[0] = *(const float4*)&Ys[k][ty * 8];
      *(float4*)&a[4] = *(const float4*)&Ys[k][ty * 8 + 4];
      *(float4*)&b[0] = *(const float4*)&Ys[k][tx * 8];
      *(float4*)&b[4] = *(const float4*)&Ys[k][tx * 8 + 4];
#pragma unroll
      for (int i = 0; i < 8; ++i)
#pragma unroll
        for (int j = 0; j < 8; ++j) acc[i][j] = fmaf(a[i], b[j], acc[i][j]);
    }
    if (tid < kCI) {
#pragma unroll 8
      for (int k = 0; k < 64; ++k) syacc += Ys[k][tid];
    }
    __syncthreads();
  }
  float* pb = part_syy + (size_t)blockIdx.x * (kCI * kCI);
#pragma unroll
  for (int i = 0; i < 8; ++i)
#pragma unroll
    for (int j = 0; j < 8; ++j) pb[(ty * 8 + i) * kCI + (tx * 8 + j)] = acc[i][j];
  if (tid < kCI) part_sy[blockIdx.x * kCI + tid] = syacc;
}

__global__ __launch_bounds__(256) void k_reduce(const float* __restrict__ part_syy,
                                                const float* __restrict__ part_sy,
                                                float* __restrict__ syy, float* __restrict__ sy) {
  if (blockIdx.x < 64) {
    int i = blockIdx.x * 256 + threadIdx.x;
    float s = 0.f;
    for (int b = 0; b < SYY_BLOCKS; ++b) s += part_syy[(size_t)b * (kCI * kCI) + i];
    syy[i] = s;
  } else if (threadIdx.x < kCI) {
    float s = 0.f;
    for (int b = 0; b < SYY_BLOCKS; ++b) s += part_sy[b * kCI + threadIdx.x];
    sy[threadIdx.x] = s;
  }
}

// ---------- BN scale/shift per output channel from (Sy, Syy) ----------
__global__ __launch_bounds__(128) void k_stats(const float* __restrict__ syy, const float* __restrict__ sy,
                                               const float* __restrict__ Ww, const float* __restrict__ bw,
                                               const float* __restrict__ gamma, const float* __restrict__ beta,
                                               float* __restrict__ scale, float* __restrict__ shift) {
  int c2 = blockIdx.x;
  int tid = threadIdx.x;
  __shared__ float w[kCI];
  __shared__ float red1[kCI], red2[kCI];
  w[tid] = Ww[c2 * kCI + tid];
  __syncthreads();
  float val = 0.f;
#pragma unroll 8
  for (int ci = 0; ci < kCI; ++ci) val = fmaf(w[ci], syy[ci * kCI + tid], val);
  red1[tid] = w[tid] * sy[tid];
  red2[tid] = val * w[tid];
  __syncthreads();
  for (int s = 64; s > 0; s >>= 1) {
    if (tid < s) { red1[tid] += red1[tid + s]; red2[tid] += red2[tid + s]; }
    __syncthreads();
  }
  if (tid == 0) {
    const float invS = 1.0f / (float)kSAMP;
    float m1 = red1[0] * invS;        // Ww . Sy / S
    float b = bw[c2];
    float mu = m1 + b;
    float e2 = red2[0] * invS + 2.f * b * m1 + b * b;  // E[wy^2]
    float var = e2 - mu * mu;
    float rstd = rsqrtf(var + 1e-5f);
    float sc = rstd * gamma[c2];
    scale[c2] = sc;
    shift[c2] = beta[c2] + (b - mu) * sc;  // out = acc*scale + shift + x
  }
}

extern "C" void kernel_launch(void* const* d_in, const int* in_sizes, int n_in,
                              void* d_out, int out_size, void* d_ws, size_t ws_size,
                              hipStream_t stream) {
  const float* x     = (const float*)d_in[0];
  const float* Wg    = (const float*)d_in[1];
  const float* bg    = (const float*)d_in[2];
  const float* Wth   = (const float*)d_in[3];
  const float* bth   = (const float*)d_in[4];
  const float* Wph   = (const float*)d_in[5];
  const float* bph   = (const float*)d_in[6];
  const float* Ww    = (const float*)d_in[7];
  const float* bw    = (const float*)d_in[8];
  const float* gamma = (const float*)d_in[9];
  const float* beta  = (const float*)d_in[10];
  float* out = (float*)d_out;

  float* wsf   = (float*)d_ws;
  float* xmean = wsf;                  // 2,097,152
  float* theta = wsf + 2097152;        // 1,048,576
  float* phi   = wsf + 3145728;        // 1,048,576
  float* f     = wsf + 4194304;        // 2,097,152
  float* psyy  = wsf + 6291456;        // 400*16384 = 6,553,600
  float* psy   = wsf + 12845056;       // 400*128 = 51,200
  float* syy   = wsf + 12896256;       // 16,384
  float* sy    = wsf + 12912640;       // 128
  float* scale = wsf + 12912768;       // 256
  float* shift = wsf + 12913024;       // 256
  u16* g2 = (u16*)(wsf + 12913280);           // [N,T,CI,V] bf16: 26,214,400
  u16* yb = g2 + (size_t)26214400;            // [N,CI,T,V] bf16: 26,214,400

  k_xmean<<<8192, 256, 0, stream>>>(x, xmean);
  k_thetaphi<<<4096, 256, 0, stream>>>(xmean, Wth, bth, Wph, bph, theta, phi);
  k_fsm<<<8192, 256, 0, stream>>>(theta, phi, f);
  k_gemm<128, kCI, kC, kTV, 0, float><<<dim3(100, 1, 32), 256, 0, stream>>>(
      Wg, x, bg, (void*)g2, nullptr, nullptr, nullptr);
  k_gemm<256, kT, kT, kCIV, 1, u16><<<dim3(50, 1, 32), 256, 0, stream>>>(
      f, g2, nullptr, (void*)yb, nullptr, nullptr, nullptr);
  k_syy<<<SYY_BLOCKS, 256, 0, stream>>>(yb, psyy, psy);
  k_reduce<<<65, 256, 0, stream>>>(psyy, psy, syy, sy);
  k_stats<<<256, 128, 0, stream>>>(syy, sy, Ww, bw, gamma, beta, scale, shift);
  k_gemm<256, kC, kCI, kTV, 2, u16><<<dim3(100, 1, 32), 256, 0, stream>>>(
      Ww, yb, nullptr, (void*)out, scale, shift, x);
}

// Round 2
// 431.611 us; speedup vs baseline: 2.3156x; 2.3156x over previous
//
#include <hip/hip_runtime.h>

typedef unsigned short u16;
using s8v = __attribute__((ext_vector_type(8))) short;   // 8 x bf16 (4 VGPRs)
using f4v = __attribute__((ext_vector_type(4))) float;   // MFMA accumulator

constexpr int kN = 32, kC = 256, kT = 256, kV = 25, kCI = 128;
constexpr int kTV = kT * kV;        // 6400
constexpr int kCIV = kCI * kV;      // 3200
constexpr int kSAMP = kN * kT * kV; // 204800
constexpr int SYY_B = 640;          // 32 n * 20 chunks, 320 k each

__device__ __forceinline__ float bf2f(u16 v) {
  return __uint_as_float(((unsigned)v) << 16);
}
__device__ __forceinline__ u16 f2bf(float f) {
  unsigned u = __float_as_uint(f);
  return (u16)((u + 0x7FFFu + ((u >> 16) & 1u)) >> 16);
}

// ---------- 1) xmean[n,c,t] = mean_v x[n,c,t,v] ----------
__global__ __launch_bounds__(256) void k_xmean(const float* __restrict__ x, float* __restrict__ xm) {
  __shared__ float sm[6400];
  size_t base = (size_t)blockIdx.x * 6400;
  const float4* src = (const float4*)(x + base);
  for (int i = threadIdx.x; i < 1600; i += 256) ((float4*)sm)[i] = src[i];
  __syncthreads();
  const float* r = sm + threadIdx.x * 25;  // stride 25: gcd(25,32)=1 -> 2-way max
  float s = 0.f;
#pragma unroll
  for (int j = 0; j < 25; ++j) s += r[j];
  xm[(size_t)blockIdx.x * 256 + threadIdx.x] = s * (1.0f / kV);
}

// ---------- 2) theta/phi ----------
__global__ __launch_bounds__(256) void k_thetaphi(
    const float* __restrict__ xmean, const float* __restrict__ Wth, const float* __restrict__ bth,
    const float* __restrict__ Wph, const float* __restrict__ bph,
    float* __restrict__ theta, float* __restrict__ phi) {
  int n = blockIdx.x >> 7;
  int o = blockIdx.x & 127;
  int t = threadIdx.x;
  __shared__ float wt[kC], wp[kC];
  wt[t] = Wth[o * kC + t];
  wp[t] = Wph[o * kC + t];
  __syncthreads();
  const float* xm = xmean + (size_t)n * kC * kT + t;
  float at = 0.f, ap = 0.f;
#pragma unroll 8
  for (int c = 0; c < kC; ++c) {
    float xv = xm[c * kT];
    at = fmaf(wt[c], xv, at);
    ap = fmaf(wp[c], xv, ap);
  }
  size_t idx = ((size_t)n * kCI + o) * kT + t;
  theta[idx] = at + bth[o];
  phi[idx] = ap + bph[o];
}

// ---------- 3) f[n,t,:] = softmax(...) -> bf16 ----------
__global__ __launch_bounds__(256) void k_fsm(const float* __restrict__ theta, const float* __restrict__ phi,
                                             u16* __restrict__ f) {
  int n = blockIdx.x >> 8;
  int t = blockIdx.x & 255;
  int tp = threadIdx.x;
  __shared__ float th[kCI];
  __shared__ float red[256];
  if (tp < kCI) th[tp] = theta[((size_t)n * kCI + tp) * kT + t];
  __syncthreads();
  const float* ph = phi + (size_t)n * kCI * kT + tp;
  float acc = 0.f;
#pragma unroll 8
  for (int o = 0; o < kCI; ++o) acc = fmaf(th[o], ph[o * kT], acc);
  red[tp] = acc;
  __syncthreads();
  for (int s = 128; s > 0; s >>= 1) {
    if (tp < s) red[tp] = fmaxf(red[tp], red[tp + s]);
    __syncthreads();
  }
  float m = red[0];
  __syncthreads();
  float e = __expf(acc - m);
  red[tp] = e;
  __syncthreads();
  for (int s = 128; s > 0; s >>= 1) {
    if (tp < s) red[tp] += red[tp + s];
    __syncthreads();
  }
  f[(size_t)blockIdx.x * 256 + tp] = f2bf(e * (1.0f / red[0]));
}

// ---------- convert Wg, Ww to fragment-linear bf16: idx = ((k>>3)*M + m)*8 + (k&7) ----------
__global__ __launch_bounds__(256) void k_cvtW(const float* __restrict__ Wg, const float* __restrict__ Ww,
                                              u16* __restrict__ Wg_fl, u16* __restrict__ Ww_fl) {
  int i = blockIdx.x * 256 + threadIdx.x;  // 0..32767
  { int m = i >> 8, k = i & 255; Wg_fl[(size_t)((k >> 3) * 128 + m) * 8 + (k & 7)] = f2bf(Wg[i]); }
  { int m = i >> 7, k = i & 127; Ww_fl[(size_t)((k >> 3) * 256 + m) * 8 + (k & 7)] = f2bf(Ww[i]); }
}

// ---------- MFMA GEMM: C_n[M,NCOLS-tile] = A @ B_n ----------
// MODE 0: g    (A=Wg_fl M=128, B=x f32 stride 6400, +bias, out g2 [N][T][CI*V] bf16)
// MODE 1: attn (A=f_bf row-major [n][256][256], B=g2 stride 3200, out yb [N][CI][T*V] bf16)
// MODE 2: wy   (A=Ww_fl M=256, B=yb stride 6400, BN+residual, out f32 [N][C][T*V])
template <int K_TOT, int NCOLS, int MODE, typename TB>
__global__ __launch_bounds__(256) void k_gemm(
    const u16* __restrict__ A_, const TB* __restrict__ B_, const float* __restrict__ bias,
    void* __restrict__ outp, const float* __restrict__ scale, const float* __restrict__ shift,
    const float* __restrict__ xres) {
  constexpr int KSTEPS = K_TOT / 32;
  constexpr int M_TOT = (MODE == 0) ? 128 : 256;
  __shared__ uint4 Bs[512];  // frag blocks [ksub][col] of 8 bf16, XOR-swizzled
  const int n = blockIdx.z, m0 = blockIdx.y * 128, n0 = blockIdx.x * 128;
  const int tid = threadIdx.x, lane = tid & 63, w = tid >> 6;
  const int wr = (w >> 1) * 64, wc = (w & 1) * 64;
  const int l15 = lane & 15, l4 = lane >> 4;
  const TB* Bn = B_ + (size_t)n * K_TOT * NCOLS + n0;
  const int scol = tid & 127, sk0 = tid >> 7;
  f4v acc[4][4];
#pragma unroll
  for (int i = 0; i < 4; ++i)
#pragma unroll
    for (int j = 0; j < 4; ++j) acc[i][j] = f4v{0.f, 0.f, 0.f, 0.f};

  for (int ks = 0; ks < KSTEPS; ++ks) {
    __syncthreads();
#pragma unroll
    for (int p = 0; p < 2; ++p) {
      int ksub = sk0 + p * 2;
      const TB* src = Bn + (size_t)(ks * 32 + ksub * 8) * NCOLS + scol;
      union { u16 u[8]; uint4 v; } pk;
#pragma unroll
      for (int j = 0; j < 8; ++j) {
        if constexpr (sizeof(TB) == 2) pk.u[j] = src[(size_t)j * NCOLS];
        else pk.u[j] = f2bf(src[(size_t)j * NCOLS]);
      }
      int blk = ksub * 128 + scol;
      blk ^= (blk >> 2) & 3;
      Bs[blk] = pk.v;
    }
    __syncthreads();
    s8v af[4];
#pragma unroll
    for (int f = 0; f < 4; ++f) {
      int m = m0 + wr + f * 16 + l15;
      const u16* ap;
      if constexpr (MODE == 1)
        ap = A_ + ((size_t)(n * 256 + m) * 256 + ks * 32 + l4 * 8);
      else
        ap = A_ + (size_t)((ks * 4 + l4) * M_TOT + m) * 8;
      af[f] = *(const s8v*)ap;
    }
#pragma unroll
    for (int g = 0; g < 4; ++g) {
      int blk = l4 * 128 + wc + g * 16 + l15;
      blk ^= (blk >> 2) & 3;
      s8v bf = *(const s8v*)&Bs[blk];
#pragma unroll
      for (int f = 0; f < 4; ++f)
        acc[f][g] = __builtin_amdgcn_mfma_f32_16x16x32_bf16(af[f], bf, acc[f][g], 0, 0, 0);
    }
  }
#pragma unroll
  for (int f = 0; f < 4; ++f) {
    int growb = m0 + wr + f * 16 + l4 * 4;
#pragma unroll
    for (int g = 0; g < 4; ++g) {
      int gcol = n0 + wc + g * 16 + l15;
#pragma unroll
      for (int r = 0; r < 4; ++r) {
        int grow = growb + r;
        float vv = acc[f][g][r];
        if constexpr (MODE == 0) {
          vv += bias[grow];
          int t = gcol / 25, v5 = gcol - t * 25;
          ((u16*)outp)[((size_t)n * kT + t) * kCIV + grow * 25 + v5] = f2bf(vv);
        } else if constexpr (MODE == 1) {
          int ci = gcol / 25, v5 = gcol - ci * 25;
          ((u16*)outp)[((size_t)n * kCI + ci) * kTV + grow * 25 + v5] = f2bf(vv);
        } else {
          size_t idx = ((size_t)n * kC + grow) * kTV + gcol;
          ((float*)outp)[idx] = vv * scale[grow] + shift[grow] + xres[idx];
        }
      }
    }
  }
}

// ---------- Syy = Y Y^T + Sy, MFMA, zero LDS (both operands k-contiguous rows of yb) ----------
__global__ __launch_bounds__(256) void k_syy(const u16* __restrict__ yb, float* __restrict__ psyy,
                                             float* __restrict__ psy) {
  const int b = blockIdx.x, n = b / 20, kc = b % 20;
  const int kbase = kc * 320;
  const int tid = threadIdx.x, lane = tid & 63, w = tid >> 6;
  const int wr = (w >> 1) * 64, wc = (w & 1) * 64, l15 = lane & 15, l4 = lane >> 4;
  const u16* Y = yb + (size_t)n * kCI * kTV;
  f4v acc[4][4];
#pragma unroll
  for (int i = 0; i < 4; ++i)
#pragma unroll
    for (int j = 0; j < 4; ++j) acc[i][j] = f4v{0.f, 0.f, 0.f, 0.f};
  float syl[4] = {0.f, 0.f, 0.f, 0.f};
  for (int ks = 0; ks < 10; ++ks) {
    int k = kbase + ks * 32 + l4 * 8;
    s8v af[4], bf[4];
#pragma unroll
    for (int f = 0; f < 4; ++f) {
      af[f] = *(const s8v*)(Y + (size_t)(wr + f * 16 + l15) * kTV + k);
      bf[f] = *(const s8v*)(Y + (size_t)(wc + f * 16 + l15) * kTV + k);
    }
#pragma unroll
    for (int f = 0; f < 4; ++f)
#pragma unroll
      for (int j = 0; j < 8; ++j) syl[f] += bf2f((u16)af[f][j]);
#pragma unroll
    for (int g = 0; g < 4; ++g)
#pragma unroll
      for (int f = 0; f < 4; ++f)
        acc[f][g] = __builtin_amdgcn_mfma_f32_16x16x32_bf16(af[f], bf[g], acc[f][g], 0, 0, 0);
  }
  float* pb = psyy + (size_t)b * 16384;
#pragma unroll
  for (int f = 0; f < 4; ++f)
#pragma unroll
    for (int g = 0; g < 4; ++g)
#pragma unroll
      for (int r = 0; r < 4; ++r)
        pb[(wr + f * 16 + l4 * 4 + r) * kCI + wc + g * 16 + l15] = acc[f][g][r];
#pragma unroll
  for (int f = 0; f < 4; ++f) {
    float s = syl[f];
    s += __shfl_xor(s, 16);
    s += __shfl_xor(s, 32);
    if ((w & 1) == 0 && l4 == 0) psy[b * kCI + wr + f * 16 + l15] = s;
  }
}

__global__ __launch_bounds__(256) void k_reduce1(const float* __restrict__ psyy, float* __restrict__ ps2) {
  int outi = (blockIdx.x & 63) * 256 + threadIdx.x;
  int kseg = blockIdx.x >> 6;  // 0..15, 40 partials each
  float s = 0.f;
  for (int b = 0; b < 40; ++b) s += psyy[(size_t)(kseg * 40 + b) * 16384 + outi];
  ps2[(size_t)kseg * 16384 + outi] = s;
}

__global__ __launch_bounds__(256) void k_reduce2(const float* __restrict__ ps2, const float* __restrict__ psy,
                                                 float* __restrict__ syy, float* __restrict__ sy) {
  if (blockIdx.x < 64) {
    int i = blockIdx.x * 256 + threadIdx.x;
    float s = 0.f;
#pragma unroll
    for (int kk = 0; kk < 16; ++kk) s += ps2[(size_t)kk * 16384 + i];
    syy[i] = s;
  } else if (threadIdx.x < kCI) {
    float s = 0.f;
    for (int b = 0; b < SYY_B; ++b) s += psy[b * kCI + threadIdx.x];
    sy[threadIdx.x] = s;
  }
}

__global__ __launch_bounds__(128) void k_stats(const float* __restrict__ syy, const float* __restrict__ sy,
                                               const float* __restrict__ Ww, const float* __restrict__ bw,
                                               const float* __restrict__ gamma, const float* __restrict__ beta,
                                               float* __restrict__ scale, float* __restrict__ shift) {
  int c2 = blockIdx.x;
  int tid = threadIdx.x;
  __shared__ float wsm[kCI];
  __shared__ float red1[kCI], red2[kCI];
  wsm[tid] = Ww[c2 * kCI + tid];
  __syncthreads();
  float val = 0.f;
#pragma unroll 8
  for (int ci = 0; ci < kCI; ++ci) val = fmaf(wsm[ci], syy[ci * kCI + tid], val);
  red1[tid] = wsm[tid] * sy[tid];
  red2[tid] = val * wsm[tid];
  __syncthreads();
  for (int s = 64; s > 0; s >>= 1) {
    if (tid < s) { red1[tid] += red1[tid + s]; red2[tid] += red2[tid + s]; }
    __syncthreads();
  }
  if (tid == 0) {
    const float invS = 1.0f / (float)kSAMP;
    float m1 = red1[0] * invS;
    float b = bw[c2];
    float mu = m1 + b;
    float e2 = red2[0] * invS + 2.f * b * m1 + b * b;
    float var = e2 - mu * mu;
    float rstd = rsqrtf(var + 1e-5f);
    float sc = rstd * gamma[c2];
    scale[c2] = sc;
    shift[c2] = beta[c2] + (b - mu) * sc;
  }
}

extern "C" void kernel_launch(void* const* d_in, const int* in_sizes, int n_in,
                              void* d_out, int out_size, void* d_ws, size_t ws_size,
                              hipStream_t stream) {
  const float* x     = (const float*)d_in[0];
  const float* Wg    = (const float*)d_in[1];
  const float* bg    = (const float*)d_in[2];
  const float* Wth   = (const float*)d_in[3];
  const float* bth   = (const float*)d_in[4];
  const float* Wph   = (const float*)d_in[5];
  const float* bph   = (const float*)d_in[6];
  const float* Ww    = (const float*)d_in[7];
  const float* bw    = (const float*)d_in[8];
  const float* gamma = (const float*)d_in[9];
  const float* beta  = (const float*)d_in[10];
  float* out = (float*)d_out;

  char* wsb = (char*)d_ws;
  float* xmean = (float*)(wsb);                    // 8 MB
  float* theta = (float*)(wsb + (8u << 20));       // 4 MB
  float* phi   = (float*)(wsb + (12u << 20));      // 4 MB
  u16*   f_bf  = (u16*)(wsb + (16u << 20));        // 4 MB
  float* ps2   = (float*)(wsb + (20u << 20));      // 1 MB
  float* psy   = (float*)(wsb + (21u << 20));      // 0.33 MB
  float* syy   = (float*)(wsb + (22u << 20));      // 64 KB
  float* sy    = syy + 16384;
  float* scale = sy + 128;
  float* shift = scale + 256;
  u16* Wg_fl = (u16*)(wsb + (23u << 20));          // 64 KB
  u16* Ww_fl = Wg_fl + 32768;                      // 64 KB
  u16* g2    = (u16*)(wsb + (24u << 20));          // 52.43 MB [N][T][CI*V]
  float* psyy = (float*)(wsb + (24u << 20));       // 41.94 MB, aliases g2 (dead after attn)
  u16* yb    = (u16*)(wsb + (80u << 20));          // 52.43 MB [N][CI][T*V]

  k_xmean<<<8192, 256, 0, stream>>>(x, xmean);
  k_cvtW<<<128, 256, 0, stream>>>(Wg, Ww, Wg_fl, Ww_fl);
  k_thetaphi<<<4096, 256, 0, stream>>>(xmean, Wth, bth, Wph, bph, theta, phi);
  k_fsm<<<8192, 256, 0, stream>>>(theta, phi, f_bf);
  k_gemm<256, kTV, 0, float><<<dim3(50, 1, 32), 256, 0, stream>>>(
      Wg_fl, x, bg, (void*)g2, nullptr, nullptr, nullptr);
  k_gemm<256, kCIV, 1, u16><<<dim3(25, 2, 32), 256, 0, stream>>>(
      f_bf, g2, nullptr, (void*)yb, nullptr, nullptr, nullptr);
  k_syy<<<SYY_B, 256, 0, stream>>>(yb, psyy, psy);
  k_reduce1<<<1024, 256, 0, stream>>>(psyy, ps2);
  k_reduce2<<<65, 256, 0, stream>>>(ps2, psy, syy, sy);
  k_stats<<<256, 128, 0, stream>>>(syy, sy, Ww, bw, gamma, beta, scale, shift);
  k_gemm<128, kTV, 2, u16><<<dim3(50, 2, 32), 256, 0, stream>>>(
      Ww_fl, yb, nullptr, (void*)out, scale, shift, x);
}

// Round 3
// 363.471 us; speedup vs baseline: 2.7497x; 1.1875x over previous
//
#include <hip/hip_runtime.h>

typedef unsigned short u16;
using s8v = __attribute__((ext_vector_type(8))) short;   // 8 x bf16 (4 VGPRs)
using f4v = __attribute__((ext_vector_type(4))) float;   // MFMA accumulator

constexpr int kN = 32, kC = 256, kT = 256, kV = 25, kCI = 128;
constexpr int kTV = kT * kV;        // 6400
constexpr int kCIV = kCI * kV;      // 3200
constexpr int kSAMP = kN * kT * kV; // 204800
constexpr int SYY_B = 256;          // 32 n * 8 chunks, 800 k each (1 block/CU)

__device__ __forceinline__ float bf2f(u16 v) {
  return __uint_as_float(((unsigned)v) << 16);
}
__device__ __forceinline__ u16 f2bf(float f) {
  unsigned u = __float_as_uint(f);
  return (u16)((u + 0x7FFFu + ((u >> 16) & 1u)) >> 16);
}

// ---------- 1) prep: x -> x_bf (bf16, same layout) + xmean over V ----------
__global__ __launch_bounds__(256) void k_prep(const float* __restrict__ x, u16* __restrict__ x_bf,
                                              float* __restrict__ xm) {
  __shared__ float sm[6400];
  size_t base = (size_t)blockIdx.x * 6400;
  const float4* src = (const float4*)(x + base);
  ushort4* dst = (ushort4*)(x_bf + base);
  for (int i = threadIdx.x; i < 1600; i += 256) {
    float4 v = src[i];
    ((float4*)sm)[i] = v;
    ushort4 b;
    b.x = f2bf(v.x); b.y = f2bf(v.y); b.z = f2bf(v.z); b.w = f2bf(v.w);
    dst[i] = b;
  }
  __syncthreads();
  const float* r = sm + threadIdx.x * 25;  // stride 25: gcd(25,32)=1
  float s = 0.f;
#pragma unroll
  for (int j = 0; j < 25; ++j) s += r[j];
  xm[(size_t)blockIdx.x * 256 + threadIdx.x] = s * (1.0f / kV);
}

// ---------- 2) thetaT/phiT [n][t][o] bf16 (k-contiguous for the f-MFMA) ----------
__global__ __launch_bounds__(256) void k_thetaphi(
    const float* __restrict__ xmean, const float* __restrict__ Wth, const float* __restrict__ bth,
    const float* __restrict__ Wph, const float* __restrict__ bph,
    u16* __restrict__ thT, u16* __restrict__ phT) {
  int n = blockIdx.x >> 5;
  int o0 = (blockIdx.x & 31) * 4;
  int t = threadIdx.x;
  __shared__ float wt[4][kC], wp[4][kC];
  for (int i = threadIdx.x; i < 1024; i += 256) {
    wt[i >> 8][i & 255] = Wth[(o0 + (i >> 8)) * kC + (i & 255)];
    wp[i >> 8][i & 255] = Wph[(o0 + (i >> 8)) * kC + (i & 255)];
  }
  __syncthreads();
  const float* xmp = xmean + (size_t)n * kC * kT + t;
  float a[4], p[4];
#pragma unroll
  for (int j = 0; j < 4; ++j) { a[j] = bth[o0 + j]; p[j] = bph[o0 + j]; }
#pragma unroll 4
  for (int c = 0; c < kC; ++c) {
    float xv = xmp[c * kT];  // coalesced across t
#pragma unroll
    for (int j = 0; j < 4; ++j) {
      a[j] = fmaf(wt[j][c], xv, a[j]);
      p[j] = fmaf(wp[j][c], xv, p[j]);
    }
  }
  size_t rowb = ((size_t)n * kT + t) * kCI + o0;
#pragma unroll
  for (int j = 0; j < 4; ++j) {
    thT[rowb + j] = f2bf(a[j]);
    phT[rowb + j] = f2bf(p[j]);
  }
}

// ---------- 3) f = softmax(theta^T phi) via MFMA; D-tile = f^T so softmax axis is M ----------
__global__ __launch_bounds__(512) void k_fmfma(const u16* __restrict__ thT, const u16* __restrict__ phT,
                                               u16* __restrict__ f) {
  const int n = blockIdx.x >> 1;
  const int tc0 = (blockIdx.x & 1) * 128;  // t (col) block
  const int tid = threadIdx.x, lane = tid & 63, w = tid >> 6;
  const int wM = w & 3, wr = wM * 64, wc = (w >> 2) * 64;
  const int l15 = lane & 15, l4 = lane >> 4;
  __shared__ float redm[4][128], reds[4][128];
  f4v acc[4][4];
#pragma unroll
  for (int i = 0; i < 4; ++i)
#pragma unroll
    for (int j = 0; j < 4; ++j) acc[i][j] = f4v{0.f, 0.f, 0.f, 0.f};
#pragma unroll
  for (int ks = 0; ks < 4; ++ks) {
    s8v af[4], bf[4];
#pragma unroll
    for (int fi = 0; fi < 4; ++fi)
      af[fi] = *(const s8v*)(phT + ((size_t)(n * 256 + wr + fi * 16 + l15) * kCI + ks * 32 + l4 * 8));
#pragma unroll
    for (int g = 0; g < 4; ++g)
      bf[g] = *(const s8v*)(thT + ((size_t)(n * 256 + tc0 + wc + g * 16 + l15) * kCI + ks * 32 + l4 * 8));
#pragma unroll
    for (int g = 0; g < 4; ++g)
#pragma unroll
      for (int fi = 0; fi < 4; ++fi)
        acc[fi][g] = __builtin_amdgcn_mfma_f32_16x16x32_bf16(af[fi], bf[g], acc[fi][g], 0, 0, 0);
  }
  // D[r=t'][c=t]; softmax over t' (rows = M dim, fully in block)
  float mx[4], sm[4];
#pragma unroll
  for (int g = 0; g < 4; ++g) {
    float m = -1e30f;
#pragma unroll
    for (int fi = 0; fi < 4; ++fi)
#pragma unroll
      for (int r = 0; r < 4; ++r) m = fmaxf(m, acc[fi][g][r]);
    m = fmaxf(m, __shfl_xor(m, 16));
    m = fmaxf(m, __shfl_xor(m, 32));
    mx[g] = m;
  }
  if (l4 == 0)
#pragma unroll
    for (int g = 0; g < 4; ++g) redm[wM][wc + g * 16 + l15] = mx[g];
  __syncthreads();
#pragma unroll
  for (int g = 0; g < 4; ++g) {
    int col = wc + g * 16 + l15;
    mx[g] = fmaxf(fmaxf(redm[0][col], redm[1][col]), fmaxf(redm[2][col], redm[3][col]));
  }
#pragma unroll
  for (int g = 0; g < 4; ++g) {
    float s = 0.f;
#pragma unroll
    for (int fi = 0; fi < 4; ++fi)
#pragma unroll
      for (int r = 0; r < 4; ++r) {
        float e = __expf(acc[fi][g][r] - mx[g]);
        acc[fi][g][r] = e;
        s += e;
      }
    s += __shfl_xor(s, 16);
    s += __shfl_xor(s, 32);
    sm[g] = s;
  }
  if (l4 == 0)
#pragma unroll
    for (int g = 0; g < 4; ++g) reds[wM][wc + g * 16 + l15] = sm[g];
  __syncthreads();
#pragma unroll
  for (int g = 0; g < 4; ++g) {
    int col = wc + g * 16 + l15;
    float inv = 1.0f / (reds[0][col] + reds[1][col] + reds[2][col] + reds[3][col]);
    int t = tc0 + col;
#pragma unroll
    for (int fi = 0; fi < 4; ++fi) {
      int tp0 = wr + fi * 16 + l4 * 4;
      ushort4 st;
      st.x = f2bf(acc[fi][g][0] * inv);
      st.y = f2bf(acc[fi][g][1] * inv);
      st.z = f2bf(acc[fi][g][2] * inv);
      st.w = f2bf(acc[fi][g][3] * inv);
      *(ushort4*)(f + (size_t)(n * 256 + t) * 256 + tp0) = st;
    }
  }
}

// ---------- convert Wg, Ww to fragment-linear bf16: idx = ((k>>3)*M + m)*8 + (k&7) ----------
__global__ __launch_bounds__(256) void k_cvtW(const float* __restrict__ Wg, const float* __restrict__ Ww,
                                              u16* __restrict__ Wg_fl, u16* __restrict__ Ww_fl) {
  int i = blockIdx.x * 256 + threadIdx.x;  // 0..32767
  { int m = i >> 8, k = i & 255; Wg_fl[(size_t)((k >> 3) * 128 + m) * 8 + (k & 7)] = f2bf(Wg[i]); }
  { int m = i >> 7, k = i & 127; Ww_fl[(size_t)((k >> 3) * 256 + m) * 8 + (k & 7)] = f2bf(Ww[i]); }
}

// ---------- MFMA GEMM: C_n[M,128-tile] = A @ B_n ----------
// MODE 0: g    (A=Wg_fl M=128, B=x_bf stride 6400, +bias, out g2 [N][T][CI*V] bf16)
// MODE 1: attn (A=f_bf row-major [n][256][256], B=g2 stride 3200, out yb [N][CI][T*V] bf16)
// MODE 2: wy   (A=Ww_fl M=256, B=yb stride 6400, BN+residual(bf16), out f32 [N][C][T*V])
template <int K_TOT, int NCOLS, int MODE>
__global__ __launch_bounds__(256) void k_gemm(
    const u16* __restrict__ A_, const u16* __restrict__ B_, const float* __restrict__ bias,
    void* __restrict__ outp, const float* __restrict__ scale, const float* __restrict__ shift,
    const u16* __restrict__ xres) {
  constexpr int KSTEPS = K_TOT / 32;
  constexpr int M_TOT = (MODE == 0) ? 128 : 256;
  __shared__ uint4 Bs[512];  // frag blocks [ksub][col] of 8 bf16, XOR-swizzled
  const int n = blockIdx.z, m0 = blockIdx.y * 128, n0 = blockIdx.x * 128;
  const int tid = threadIdx.x, lane = tid & 63, w = tid >> 6;
  const int wr = (w >> 1) * 64, wc = (w & 1) * 64;
  const int l15 = lane & 15, l4 = lane >> 4;
  const u16* Bn = B_ + (size_t)n * K_TOT * NCOLS + n0;
  const int scol = tid & 127, sk0 = tid >> 7;
  f4v acc[4][4];
#pragma unroll
  for (int i = 0; i < 4; ++i)
#pragma unroll
    for (int j = 0; j < 4; ++j) acc[i][j] = f4v{0.f, 0.f, 0.f, 0.f};

  for (int ks = 0; ks < KSTEPS; ++ks) {
    __syncthreads();
#pragma unroll
    for (int p = 0; p < 2; ++p) {
      int ksub = sk0 + p * 2;
      const u16* src = Bn + (size_t)(ks * 32 + ksub * 8) * NCOLS + scol;
      union { u16 u[8]; uint4 v; } pk;
#pragma unroll
      for (int j = 0; j < 8; ++j) pk.u[j] = src[(size_t)j * NCOLS];
      int blk = ksub * 128 + scol;
      blk ^= (blk >> 2) & 3;
      Bs[blk] = pk.v;
    }
    __syncthreads();
    s8v af[4];
#pragma unroll
    for (int fi = 0; fi < 4; ++fi) {
      int m = m0 + wr + fi * 16 + l15;
      const u16* ap;
      if constexpr (MODE == 1)
        ap = A_ + ((size_t)(n * 256 + m) * 256 + ks * 32 + l4 * 8);
      else
        ap = A_ + (size_t)((ks * 4 + l4) * M_TOT + m) * 8;
      af[fi] = *(const s8v*)ap;
    }
#pragma unroll
    for (int g = 0; g < 4; ++g) {
      int blk = l4 * 128 + wc + g * 16 + l15;
      blk ^= (blk >> 2) & 3;
      s8v bf = *(const s8v*)&Bs[blk];
#pragma unroll
      for (int fi = 0; fi < 4; ++fi)
        acc[fi][g] = __builtin_amdgcn_mfma_f32_16x16x32_bf16(af[fi], bf, acc[fi][g], 0, 0, 0);
    }
  }
#pragma unroll
  for (int fi = 0; fi < 4; ++fi) {
    int growb = m0 + wr + fi * 16 + l4 * 4;
#pragma unroll
    for (int g = 0; g < 4; ++g) {
      int gcol = n0 + wc + g * 16 + l15;
#pragma unroll
      for (int r = 0; r < 4; ++r) {
        int grow = growb + r;
        float vv = acc[fi][g][r];
        if constexpr (MODE == 0) {
          vv += bias[grow];
          int t = gcol / 25, v5 = gcol - t * 25;
          ((u16*)outp)[((size_t)n * kT + t) * kCIV + grow * 25 + v5] = f2bf(vv);
        } else if constexpr (MODE == 1) {
          int ci = gcol / 25, v5 = gcol - ci * 25;
          ((u16*)outp)[((size_t)n * kCI + ci) * kTV + grow * 25 + v5] = f2bf(vv);
        } else {
          size_t idx = ((size_t)n * kC + grow) * kTV + gcol;
          ((float*)outp)[idx] = vv * scale[grow] + shift[grow] + bf2f(xres[idx]);
        }
      }
    }
  }
}

// ---------- Syy = Y Y^T + Sy, MFMA, zero LDS (yb rows are k-contiguous) ----------
__global__ __launch_bounds__(256) void k_syy(const u16* __restrict__ yb, float* __restrict__ psyy,
                                             float* __restrict__ psy) {
  const int b = blockIdx.x, n = b >> 3, kc = b & 7;
  const int kbase = kc * 800;
  const int tid = threadIdx.x, lane = tid & 63, w = tid >> 6;
  const int wr = (w >> 1) * 64, wc = (w & 1) * 64, l15 = lane & 15, l4 = lane >> 4;
  const u16* Y = yb + (size_t)n * kCI * kTV;
  f4v acc[4][4];
#pragma unroll
  for (int i = 0; i < 4; ++i)
#pragma unroll
    for (int j = 0; j < 4; ++j) acc[i][j] = f4v{0.f, 0.f, 0.f, 0.f};
  float syl[4] = {0.f, 0.f, 0.f, 0.f};
  for (int ks = 0; ks < 25; ++ks) {
    int k = kbase + ks * 32 + l4 * 8;
    s8v af[4], bf[4];
#pragma unroll
    for (int fi = 0; fi < 4; ++fi) {
      af[fi] = *(const s8v*)(Y + (size_t)(wr + fi * 16 + l15) * kTV + k);
      bf[fi] = *(const s8v*)(Y + (size_t)(wc + fi * 16 + l15) * kTV + k);
    }
#pragma unroll
    for (int fi = 0; fi < 4; ++fi)
#pragma unroll
      for (int j = 0; j < 8; ++j) syl[fi] += bf2f((u16)af[fi][j]);
#pragma unroll
    for (int g = 0; g < 4; ++g)
#pragma unroll
      for (int fi = 0; fi < 4; ++fi)
        acc[fi][g] = __builtin_amdgcn_mfma_f32_16x16x32_bf16(af[fi], bf[g], acc[fi][g], 0, 0, 0);
  }
  float* pb = psyy + (size_t)b * 16384;
#pragma unroll
  for (int fi = 0; fi < 4; ++fi)
#pragma unroll
    for (int g = 0; g < 4; ++g)
#pragma unroll
      for (int r = 0; r < 4; ++r)
        pb[(wr + fi * 16 + l4 * 4 + r) * kCI + wc + g * 16 + l15] = acc[fi][g][r];
#pragma unroll
  for (int fi = 0; fi < 4; ++fi) {
    float s = syl[fi];
    s += __shfl_xor(s, 16);
    s += __shfl_xor(s, 32);
    if ((w & 1) == 0 && l4 == 0) psy[b * kCI + wr + fi * 16 + l15] = s;
  }
}

__global__ __launch_bounds__(256) void k_reduce(const float* __restrict__ psyy, const float* __restrict__ psy,
                                                float* __restrict__ syy, float* __restrict__ sy) {
  if (blockIdx.x < 64) {
    int i = blockIdx.x * 256 + threadIdx.x;
    float s = 0.f;
    for (int b = 0; b < SYY_B; ++b) s += psyy[(size_t)b * 16384 + i];
    syy[i] = s;
  } else if (threadIdx.x < kCI) {
    float s = 0.f;
    for (int b = 0; b < SYY_B; ++b) s += psy[b * kCI + threadIdx.x];
    sy[threadIdx.x] = s;
  }
}

__global__ __launch_bounds__(128) void k_stats(const float* __restrict__ syy, const float* __restrict__ sy,
                                               const float* __restrict__ Ww, const float* __restrict__ bw,
                                               const float* __restrict__ gamma, const float* __restrict__ beta,
                                               float* __restrict__ scale, float* __restrict__ shift) {
  int c2 = blockIdx.x;
  int tid = threadIdx.x;
  __shared__ float wsm[kCI];
  __shared__ float red1[kCI], red2[kCI];
  wsm[tid] = Ww[c2 * kCI + tid];
  __syncthreads();
  float val = 0.f;
#pragma unroll 8
  for (int ci = 0; ci < kCI; ++ci) val = fmaf(wsm[ci], syy[ci * kCI + tid], val);
  red1[tid] = wsm[tid] * sy[tid];
  red2[tid] = val * wsm[tid];
  __syncthreads();
  for (int s = 64; s > 0; s >>= 1) {
    if (tid < s) { red1[tid] += red1[tid + s]; red2[tid] += red2[tid + s]; }
    __syncthreads();
  }
  if (tid == 0) {
    const float invS = 1.0f / (float)kSAMP;
    float m1 = red1[0] * invS;
    float b = bw[c2];
    float mu = m1 + b;
    float e2 = red2[0] * invS + 2.f * b * m1 + b * b;
    float var = e2 - mu * mu;
    float rstd = rsqrtf(var + 1e-5f);
    float sc = rstd * gamma[c2];
    scale[c2] = sc;
    shift[c2] = beta[c2] + (b - mu) * sc;
  }
}

extern "C" void kernel_launch(void* const* d_in, const int* in_sizes, int n_in,
                              void* d_out, int out_size, void* d_ws, size_t ws_size,
                              hipStream_t stream) {
  const float* x     = (const float*)d_in[0];
  const float* Wg    = (const float*)d_in[1];
  const float* bg    = (const float*)d_in[2];
  const float* Wth   = (const float*)d_in[3];
  const float* bth   = (const float*)d_in[4];
  const float* Wph   = (const float*)d_in[5];
  const float* bph   = (const float*)d_in[6];
  const float* Ww    = (const float*)d_in[7];
  const float* bw    = (const float*)d_in[8];
  const float* gamma = (const float*)d_in[9];
  const float* beta  = (const float*)d_in[10];
  float* out = (float*)d_out;

  char* wsb = (char*)d_ws;
  float* xmean = (float*)(wsb);                    // 8 MB
  u16*   thT   = (u16*)(wsb + (8u << 20));         // 2 MB  [n][t][o] bf16
  u16*   phT   = (u16*)(wsb + (10u << 20));        // 2 MB  [n][t][o] bf16
  u16*   f_bf  = (u16*)(wsb + (12u << 20));        // 4 MB  [n][t][t'] bf16
  float* psy   = (float*)(wsb + (16u << 20));      // 128 KB
  float* syy   = (float*)(wsb + (17u << 20));      // 64 KB
  float* sy    = syy + 16384;
  float* scale = sy + 128;
  float* shift = scale + 256;
  u16* Wg_fl = (u16*)(wsb + (18u << 20));          // 64 KB
  u16* Ww_fl = Wg_fl + 32768;                      // 64 KB
  u16* x_bf  = (u16*)(wsb + (19u << 20));          // 100 MB [n][c][t*v] bf16
  u16* g2    = (u16*)(wsb + (119u << 20));         // 50 MB [N][T][CI*V] bf16
  float* psyy = (float*)(wsb + (119u << 20));      // 16.8 MB, aliases g2 (dead after attn)
  u16* yb    = (u16*)(wsb + (172u << 20));         // 50 MB [N][CI][T*V] bf16

  k_prep<<<8192, 256, 0, stream>>>(x, x_bf, xmean);
  k_cvtW<<<128, 256, 0, stream>>>(Wg, Ww, Wg_fl, Ww_fl);
  k_thetaphi<<<1024, 256, 0, stream>>>(xmean, Wth, bth, Wph, bph, thT, phT);
  k_fmfma<<<64, 512, 0, stream>>>(thT, phT, f_bf);
  k_gemm<256, kTV, 0><<<dim3(50, 1, 32), 256, 0, stream>>>(
      Wg_fl, x_bf, bg, (void*)g2, nullptr, nullptr, nullptr);
  k_gemm<256, kCIV, 1><<<dim3(25, 2, 32), 256, 0, stream>>>(
      f_bf, g2, nullptr, (void*)yb, nullptr, nullptr, nullptr);
  k_syy<<<SYY_B, 256, 0, stream>>>(yb, psyy, psy);
  k_reduce<<<65, 256, 0, stream>>>(psyy, psy, syy, sy);
  k_stats<<<256, 128, 0, stream>>>(syy, sy, Ww, bw, gamma, beta, scale, shift);
  k_gemm<128, kTV, 2><<<dim3(50, 2, 32), 256, 0, stream>>>(
      Ww_fl, yb, nullptr, (void*)out, scale, shift, x_bf);
}